// Round 1
// baseline (144.560 us; speedup 1.0000x reference)
//
#include <hip/hip_runtime.h>

// x: (8, 16, 3, 256, 256) f32.  out: (128, 2, 256, 256) f32.
// out[bl, ch, hw] = (l>0) ? x[b, l, 0, hw] - x[b, l-1, 0, hw] : 0   (ch = 0,1 identical)
//
// HW = 256*256 = 65536 floats -> HW4 = 16384 float4 per plane.
// Input plane stride (per l): 3*HW floats (channels 0..2), we touch only ch 0.

__global__ __launch_bounds__(256) void dummyflow_diff_kernel(
    const float4* __restrict__ x, float4* __restrict__ out) {
    constexpr int HW4 = 65536 / 4;            // 16384 float4 per plane
    int idx = blockIdx.x * blockDim.x + threadIdx.x;   // [0, 128*16384)
    int bl  = idx >> 14;                      // plane index 0..127  (b*16 + l)
    int hw4 = idx & (HW4 - 1);
    int l   = bl & 15;

    float4 d;
    if (l == 0) {
        d = make_float4(0.f, 0.f, 0.f, 0.f);
    } else {
        const float4 cur = x[(size_t)bl       * 3 * HW4 + hw4];
        const float4 prv = x[(size_t)(bl - 1) * 3 * HW4 + hw4];
        d = make_float4(cur.x - prv.x, cur.y - prv.y, cur.z - prv.z, cur.w - prv.w);
    }

    size_t o = (size_t)bl * 2 * HW4 + hw4;    // channel 0 of output
    out[o]        = d;                        // ch 0
    out[o + HW4]  = d;                        // ch 1 (same value)
}

extern "C" void kernel_launch(void* const* d_in, const int* in_sizes, int n_in,
                              void* d_out, int out_size, void* d_ws, size_t ws_size,
                              hipStream_t stream) {
    const float4* x  = (const float4*)d_in[0];
    float4* out      = (float4*)d_out;

    constexpr int HW4 = 65536 / 4;
    const int total   = 128 * HW4;            // 2,097,152 threads
    const int block   = 256;
    const int grid    = total / block;        // 8192 blocks

    dummyflow_diff_kernel<<<grid, block, 0, stream>>>(x, out);
}